// Round 2
// baseline (369.509 us; speedup 1.0000x reference)
//
#include <hip/hip_runtime.h>

// Fold (col2im): x (8, 32, 8, 8, 4096) f32, kernel (8,8), stride (4,4),
// patch grid 64x64 -> out (8, 32, 260, 260) f32.
//
// LDS-staged gather. Block (bc, a) produces output rows h = 4a+r, r=0..3.
// These rows need exactly the 64 (di,dj) input rows:
//   di = 0..3  -> patch row i = a     (invalid for a == 64)
//   di = 4..7  -> patch row i = a - 1 (invalid for a == 0)
// i.e. 64 rows x 64 j-values = 16 KB, loaded once with aligned float4
// (each 16-lane group reads a 256B-aligned contiguous 256B segment),
// staged to LDS, then 260 output float4-quads gathered from LDS.
// Every input byte is read exactly once chip-wide; no atomics.
//
// out[h=4a+r, w=4t+k] = A + B + C + D   (reference .add order preserved):
//   A: lds[di=r  ][dj=k  ][j=t  ]   (t<64)
//   B: lds[di=r  ][dj=k+4][j=t-1]   (t>=1)
//   C: lds[di=r+4][dj=k  ][j=t  ]   (t<64, a>=1)
//   D: lds[di=r+4][dj=k+4][j=t-1]   (t>=1, a>=1)
// Edge slabs zero-fill the invalid LDS half so C/D (or A/B) are exact 0s.

#define L     4096
#define H_OUT 260
#define NB_A  65     // a = 0..64

__global__ __launch_bounds__(256) void fold_kernel(const float* __restrict__ x,
                                                   float* __restrict__ out) {
    __shared__ float lds[64 * 64];   // [row = di*8 + dj][j], 16 KB

    const int bid = blockIdx.x;
    const int a   = bid % NB_A;      // 0..64
    const int bc  = bid / NB_A;      // 0..255
    const int tid = threadIdx.x;

    const float* xb = x + (size_t)bc * (64 * L);

    // ---- load phase: 1024 float4 chunks, 4 per thread ----
    #pragma unroll
    for (int q = 0; q < 4; ++q) {
        const int c   = q * 256 + tid;
        const int row = c >> 4;       // 0..63  (di*8 + dj)
        const int pos = c & 15;       // float4 index within 64-float row
        const bool lower = row < 32;  // di < 4
        const int  i     = lower ? a : (a - 1);
        const bool valid = lower ? (a < 64) : (a > 0);
        float4 v = make_float4(0.f, 0.f, 0.f, 0.f);
        if (valid) {
            v = *reinterpret_cast<const float4*>(xb + row * L + i * 64 + pos * 4);
        }
        *reinterpret_cast<float4*>(&lds[row * 64 + pos * 4]) = v;
    }
    __syncthreads();

    // ---- compute phase: 260 output quads (threads 0..3 take a 2nd) ----
    for (int q = tid; q < 260; q += 256) {
        const int r = q / 65;        // 0..3
        const int t = q % 65;        // 0..64 ; w = 4t + k
        const int jA = (t < 64) ? t : 63;     // clamped safe indices
        const int jB = (t > 0) ? (t - 1) : 0;
        const float mA = (t < 64) ? 1.f : 0.f;
        const float mB = (t > 0) ? 1.f : 0.f;
        const float* ldsA = &lds[(r * 8) * 64];        // di = r
        const float* ldsC = &lds[((r + 4) * 8) * 64];  // di = r + 4
        float acc[4];
        #pragma unroll
        for (int k = 0; k < 4; ++k) {
            const float vA = ldsA[k * 64 + jA];
            const float vB = ldsA[(k + 4) * 64 + jB];
            const float vC = ldsC[k * 64 + jA];
            const float vD = ldsC[(k + 4) * 64 + jB];
            float s = mA * vA;      // A
            s += mB * vB;           // + B
            s += mA * vC;           // + C
            s += mB * vD;           // + D
            acc[k] = s;
        }
        const int h = 4 * a + r;
        const size_t ob = ((size_t)bc * H_OUT + h) * H_OUT + 4 * t;
        *reinterpret_cast<float4*>(out + ob) =
            make_float4(acc[0], acc[1], acc[2], acc[3]);
    }
}

extern "C" void kernel_launch(void* const* d_in, const int* in_sizes, int n_in,
                              void* d_out, int out_size, void* d_ws, size_t ws_size,
                              hipStream_t stream) {
    const float* x = (const float*)d_in[0];
    float* out     = (float*)d_out;

    const int grid  = 256 * NB_A;   // 16,640 blocks (bc x a)
    const int block = 256;

    fold_kernel<<<grid, block, 0, stream>>>(x, out);
}